// Round 16
// baseline (282.945 us; speedup 1.0000x reference)
//
#include <hip/hip_runtime.h>

typedef unsigned short u16;
typedef short s16x4 __attribute__((ext_vector_type(4)));
typedef _Float16 h16x8 __attribute__((ext_vector_type(8)));
typedef _Float16 h16x4 __attribute__((ext_vector_type(4)));
typedef _Float16 h16x2 __attribute__((ext_vector_type(2)));
typedef __fp16 fp16x2 __attribute__((ext_vector_type(2)));
typedef float f32x4 __attribute__((ext_vector_type(4)));

#define SEQ 2048
#define BATCH 4
#define M_TOK (BATCH * SEQ)  // 8192
// 1/sqrt(64) * log2(e): folded into Q so softmax is a bare exp2
#define QK_SCALE 0.18033688011112043f

#if __has_builtin(__builtin_amdgcn_exp2f)
#define EXP2(x) __builtin_amdgcn_exp2f(x)
#else
#define EXP2(x) exp2f(x)
#endif

// ---- K=32 f16 MFMA (main GEMM + QK^T) ----
#if __has_builtin(__builtin_amdgcn_mfma_f32_16x16x32_f16)
#define MFMA32(A, B, C) __builtin_amdgcn_mfma_f32_16x16x32_f16((A), (B), (C), 0, 0, 0)
#else
static __device__ __forceinline__ f32x4 mfma32_asm(h16x8 a, h16x8 b, f32x4 c) {
  asm volatile("v_mfma_f32_16x16x32_f16 %0, %1, %2, %0"
               : "+v"(c)
               : "v"(a), "v"(b));
  return c;
}
#define MFMA32(A, B, C) mfma32_asm((A), (B), (C))
#endif

// ---- K=16 f16 MFMA (PV consumes P^T straight from S^T C-layout regs) ----
#if __has_builtin(__builtin_amdgcn_mfma_f32_16x16x16f16)
#define MFMA16(A, B, C) __builtin_amdgcn_mfma_f32_16x16x16f16((A), (B), (C), 0, 0, 0)
#elif __has_builtin(__builtin_amdgcn_mfma_f32_16x16x16_f16)
#define MFMA16(A, B, C) __builtin_amdgcn_mfma_f32_16x16x16_f16((A), (B), (C), 0, 0, 0)
#else
static __device__ __forceinline__ f32x4 mfma16_asm(h16x4 a, h16x4 b, f32x4 c) {
  asm volatile("v_mfma_f32_16x16x16_f16 %0, %1, %2, %0"
               : "+v"(c)
               : "v"(a), "v"(b));
  return c;
}
#define MFMA16(A, B, C) mfma16_asm((A), (B), (C))
#endif

// f32 -> f16 (RNE) as raw u16
__device__ __forceinline__ u16 f2h(float f) {
  union { _Float16 h; u16 u; } v;
  v.h = (_Float16)f;
  return v.u;
}
// raw u16 f16 -> f32
__device__ __forceinline__ float h2f(u16 u) {
  union { u16 u; _Float16 h; } v;
  v.u = u;
  return (float)v.h;
}

// pack two f32 -> two f16 in one dword (v_cvt_pkrtz_f16_f32)
#if __has_builtin(__builtin_amdgcn_cvt_pkrtz)
static __device__ __forceinline__ h16x2 pkh2(float lo, float hi) {
  union { fp16x2 a; h16x2 b; } u;
  u.a = __builtin_amdgcn_cvt_pkrtz(lo, hi);
  return u.b;
}
#else
static __device__ __forceinline__ h16x2 pkh2(float lo, float hi) {
  h16x2 r; r[0] = (_Float16)lo; r[1] = (_Float16)hi; return r;
}
#endif
#define PKH2(lo, hi) pkh2((lo), (hi))

// async global->LDS 16B: LDS dest is wave-uniform base + lane*16
__device__ __forceinline__ void gld16(u16* lds, const u16* g) {
  __builtin_amdgcn_global_load_lds(
      (const __attribute__((address_space(1))) unsigned int*)g,
      (__attribute__((address_space(3))) unsigned int*)lds, 16, 0, 0);
}

// schedule/sync primitives for the counted-vmcnt pipeline
#define VMCNT4 asm volatile("s_waitcnt vmcnt(4)" ::: "memory")
#define VMCNT0 asm volatile("s_waitcnt vmcnt(0)" ::: "memory")
#define LGK0 asm volatile("s_waitcnt lgkmcnt(0)" ::: "memory")
#define SCHEDB __builtin_amdgcn_sched_barrier(0)
#define BARRIER                                                                \
  do {                                                                         \
    SCHEDB;                                                                    \
    __builtin_amdgcn_s_barrier();                                              \
    SCHEDB;                                                                    \
  } while (0)

// ---------------- prep: f32 -> f16 cast ----------------
__global__ __launch_bounds__(256) void cvt_f32_f16(const float* __restrict__ in,
                                                   u16* __restrict__ out) {
  int i = (blockIdx.x * 256 + threadIdx.x) * 4;
  float4 f = *(const float4*)(in + i);
  ushort4 o;
  o.x = f2h(f.x); o.y = f2h(f.y); o.z = f2h(f.z); o.w = f2h(f.w);
  *(ushort4*)(out + i) = o;
}

// ---------------- prep: W (KxN f32) -> Wt (NxK f16) ----------------
__global__ __launch_bounds__(256) void transpose_cvt(const float* __restrict__ W,
                                                     u16* __restrict__ Wt, int K, int N) {
  __shared__ float tile[32][33];
  const int tx = threadIdx.x, ty = threadIdx.y;
  const int n0 = blockIdx.x * 32, k0 = blockIdx.y * 32;
  for (int j = ty; j < 32; j += 8)
    tile[j][tx] = W[(size_t)(k0 + j) * N + n0 + tx];
  __syncthreads();
  for (int j = ty; j < 32; j += 8)
    Wt[(size_t)(n0 + j) * K + k0 + tx] = f2h(tile[tx][j]);
}

// ---------------- QKV GEMM: 128x128 tile, BK=64, counted-vmcnt pipeline ----------------
// 256 threads (4 waves, 2M x 2N; per-wave C = 64x64). Double-buffered 64KB LDS
// -> 2 blocks/CU (no scheduling tail: grid 1536 = 3 x 512 slots; cross-block overlap).
// Ledger identical to the verified 256² version (per-thread: 2 loads per kh-group):
//   entry vmcnt(4) retires {A0,B0}(t); kh0 compute issues {A0,B0}(t+1);
//   mid vmcnt(4) retires {A1,B1}(t); kh1 compute issues {A1,B1}(t+1);
//   vmcnt(0) only at last tile's mid. Never drains in steady state.
// LDS per buffer: A[kh][128 rows][32 k] 8KB/kh, B likewise at +8192 u16.
// Epilogue: round-4-verified 128x130 tile (Q/K row-major stores; V -> vt[d][s]).
__global__ __launch_bounds__(256, 2) void gemm_qkv(const u16* __restrict__ A,
                                                   const u16* __restrict__ Bt,
                                                   const float* __restrict__ bias,
                                                   u16* __restrict__ Cout,
                                                   u16* __restrict__ Vtout,
                                                   int M, int N, int K) {
  __shared__ u16 smem[32768];  // 64KB: 2 buf x (A 8192 u16 + B 8192 u16)
  const int t = threadIdx.x;
  const int lane = t & 63, wave = t >> 6;
  const int wr = wave >> 1, wc = wave & 1;
  const int lr = lane & 15, quad = lane >> 4;
  const int swzl = (lr >> 1) & 3;
  const int qs8 = ((quad ^ swzl) << 3);
  const long m0 = (long)blockIdx.y * 128, n0 = (long)blockIdx.x * 128;

  // staging map: per kh-group 512 chunks; load L in {t, t+256}:
  // row = L>>2, pc = L&3, src k-chunk = pc ^ ((row>>1)&3) = (L&3)^((L>>3)&3)
  const int L0 = t, L1 = t + 256;
  const int rS0 = L0 >> 2, sS0 = ((L0 & 3) ^ ((L0 >> 3) & 3)) * 8;
  const int rS1 = L1 >> 2, sS1 = ((L1 & 3) ^ ((L1 >> 3) & 3)) * 8;
  const u16* Ag0 = A + (m0 + rS0) * (long)K + sS0;
  const u16* Ag1 = A + (m0 + rS1) * (long)K + sS1;
  const u16* Bg0 = Bt + (n0 + rS0) * (long)K + sS0;
  const u16* Bg1 = Bt + (n0 + rS1) * (long)K + sS1;

#define STAGE_A(c, kh, gofs)                                    \
  do {                                                          \
    gld16(smem + (c)*16384 + (kh)*4096 + L0 * 8, Ag0 + (gofs)); \
    gld16(smem + (c)*16384 + (kh)*4096 + L1 * 8, Ag1 + (gofs)); \
  } while (0)
#define STAGE_B(c, kh, gofs)                                           \
  do {                                                                 \
    gld16(smem + (c)*16384 + 8192 + (kh)*4096 + L0 * 8, Bg0 + (gofs)); \
    gld16(smem + (c)*16384 + 8192 + (kh)*4096 + L1 * 8, Bg1 + (gofs)); \
  } while (0)

  // fragment read offsets (u16, within a kh sub-buffer; row stride 32 u16)
  int aoff[4], boff[4];
#pragma unroll
  for (int mf = 0; mf < 4; ++mf) aoff[mf] = (wr * 64 + mf * 16 + lr) * 32 + qs8;
#pragma unroll
  for (int nf = 0; nf < 4; ++nf) boff[nf] = (wc * 64 + nf * 16 + lr) * 32 + qs8;

  f32x4 acc[4][4];
#pragma unroll
  for (int i = 0; i < 4; ++i)
#pragma unroll
    for (int j = 0; j < 4; ++j) acc[i][j] = (f32x4){0.f, 0.f, 0.f, 0.f};

  // prologue: tile 0, issue order = ledger order {A0,B0,A1,B1}
  STAGE_A(0, 0, 0);
  STAGE_B(0, 0, 0);
  STAGE_A(0, 1, 32);
  STAGE_B(0, 1, 32);

  const int NT = K >> 6;  // 16
  for (int kt = 0; kt < NT; ++kt) {
    const int c = kt & 1, nc = c ^ 1;
    const u16* Ab = smem + c * 16384;
    const u16* Bb = Ab + 8192;
    const bool pf = (kt + 1 < NT);
    const long go = (long)(kt + 1) * 64;

    VMCNT4;  // retire {A0,B0}(kt)
    BARRIER;

    h16x8 bf[4], af[4];
    // ---- kh0 ----
    if (pf) STAGE_A(nc, 0, go);
#pragma unroll
    for (int nf = 0; nf < 4; ++nf) bf[nf] = *(const h16x8*)&Bb[boff[nf]];
#pragma unroll
    for (int mf = 0; mf < 4; ++mf) af[mf] = *(const h16x8*)&Ab[aoff[mf]];
    if (pf) STAGE_B(nc, 0, go);
    LGK0; SCHEDB;
    __builtin_amdgcn_s_setprio(1);
#pragma unroll
    for (int mf = 0; mf < 4; ++mf)
#pragma unroll
      for (int nf = 0; nf < 4; ++nf)
        acc[mf][nf] = MFMA32(af[mf], bf[nf], acc[mf][nf]);
    __builtin_amdgcn_s_setprio(0);
    SCHEDB;

    if (pf) { VMCNT4; } else { VMCNT0; }  // retire {A1,B1}(kt)
    BARRIER;

    // ---- kh1 ----
    if (pf) STAGE_A(nc, 1, go + 32);
#pragma unroll
    for (int nf = 0; nf < 4; ++nf) bf[nf] = *(const h16x8*)&Bb[4096 + boff[nf]];
#pragma unroll
    for (int mf = 0; mf < 4; ++mf) af[mf] = *(const h16x8*)&Ab[4096 + aoff[mf]];
    if (pf) STAGE_B(nc, 1, go + 32);
    LGK0; SCHEDB;
    __builtin_amdgcn_s_setprio(1);
#pragma unroll
    for (int mf = 0; mf < 4; ++mf)
#pragma unroll
      for (int nf = 0; nf < 4; ++nf)
        acc[mf][nf] = MFMA32(af[mf], bf[nf], acc[mf][nf]);
    __builtin_amdgcn_s_setprio(0);
    SCHEDB;
  }
#undef STAGE_A
#undef STAGE_B

  // ---------------- epilogue via LDS tile 128x130 (round-4 verified) ----------------
  const float qs = (n0 < 1024) ? QK_SCALE : 1.0f;
  float bv[4];
#pragma unroll
  for (int ct = 0; ct < 4; ++ct) bv[ct] = bias[n0 + wc * 64 + ct * 16 + lr];

  __syncthreads();  // staging buffers dead; reuse as 128x130 tile

  if (n0 < 2048) {
    // Q/K region: tile[row][col], then row-major coalesced 16B stores to qkv
#pragma unroll
    for (int mt = 0; mt < 4; ++mt)
#pragma unroll
      for (int ct = 0; ct < 4; ++ct) {
        const int col = wc * 64 + ct * 16 + lr;
#pragma unroll
        for (int reg = 0; reg < 4; ++reg) {
          const int row = wr * 64 + mt * 16 + quad * 4 + reg;
          smem[row * 130 + col] = f2h((acc[mt][ct][reg] + bv[ct]) * qs);
        }
      }
    __syncthreads();
#pragma unroll
    for (int i = 0; i < 8; ++i) {
      const int ch = i * 256 + t;  // 2048 chunks of 8 u16
      const int row = ch >> 4, cc = (ch & 15) * 8;
      *(uint4*)&Cout[(m0 + row) * (long)N + n0 + cc] = *(const uint4*)&smem[row * 130 + cc];
    }
  } else {
    // V region: tile[col][row] (b64 writes), then coalesced stores to vt[d][s]
#pragma unroll
    for (int mt = 0; mt < 4; ++mt)
#pragma unroll
      for (int ct = 0; ct < 4; ++ct) {
        const int col = wc * 64 + ct * 16 + lr;
        const int row = wr * 64 + mt * 16 + quad * 4;
        s16x4 ov;
#pragma unroll
        for (int reg = 0; reg < 4; ++reg)
          ov[reg] = (short)f2h(acc[mt][ct][reg] + bv[ct]);
        *(s16x4*)&smem[col * 130 + row] = ov;
      }
    __syncthreads();
    const int bb = (int)(m0 >> 11);          // batch index (m0 128-aligned, SEQ=2048)
    const int sbase = (int)(m0 & 2047);
    const long vrow0 = (long)bb * 1024 + (n0 - 2048);  // (b*16+h)*64 + d
#pragma unroll
    for (int i = 0; i < 8; ++i) {
      const int task = i * 256 + t;  // col x s-chunk
      const int col = task >> 4, s0 = (task & 15) * 8;
      *(uint4*)&Vtout[(vrow0 + col) * (long)SEQ + sbase + s0] =
          *(const uint4*)&smem[col * 130 + s0];
    }
  }
}

// ---------------- proj GEMM: 128x128 tile, BK=32 (round-4 verified structure) ----------------
__global__ __launch_bounds__(256, 3) void gemm_proj(const u16* __restrict__ A,
                                                    const u16* __restrict__ Bt,
                                                    const float* __restrict__ bias,
                                                    float* __restrict__ Cout,
                                                    int M, int N, int K) {
  __shared__ u16 smem[16640];
  const int t = threadIdx.x;
  const int lane = t & 63, wave = t >> 6;
  const int wr = wave >> 1, wc = wave & 1;
  const int lr = lane & 15, quad = lane >> 4;
  const long m0 = (long)blockIdx.y * 128, n0 = (long)blockIdx.x * 128;

  const int r0 = t >> 2,         c0 = (((t) & 3) ^ ((r0 >> 1) & 3)) * 8;
  const int r1 = (t + 256) >> 2, c1 = (((t + 256) & 3) ^ ((r1 >> 1) & 3)) * 8;
  const u16* Ag0 = A + (m0 + r0) * (long)K + c0;
  const u16* Ag1 = A + (m0 + r1) * (long)K + c1;
  const u16* Bg0 = Bt + (n0 + r0) * (long)K + c0;
  const u16* Bg1 = Bt + (n0 + r1) * (long)K + c1;
  const int swz = (lr >> 1) & 3;

  f32x4 acc[4][4];
#pragma unroll
  for (int i = 0; i < 4; ++i)
#pragma unroll
    for (int j = 0; j < 4; ++j) acc[i][j] = (f32x4){0.f, 0.f, 0.f, 0.f};

  gld16(smem + t * 8, Ag0);
  gld16(smem + t * 8 + 2048, Ag1);
  gld16(smem + 8192 + t * 8, Bg0);
  gld16(smem + 8192 + t * 8 + 2048, Bg1);

  const int NIT = K >> 5;
  for (int it = 0; it < NIT; ++it) {
    const int cur = it & 1;
    __syncthreads();
    if (it + 1 < NIT) {
      const int nx = cur ^ 1;
      const long ko = (long)(it + 1) * 32;
      gld16(smem + nx * 4096 + t * 8, Ag0 + ko);
      gld16(smem + nx * 4096 + t * 8 + 2048, Ag1 + ko);
      gld16(smem + 8192 + nx * 4096 + t * 8, Bg0 + ko);
      gld16(smem + 8192 + nx * 4096 + t * 8 + 2048, Bg1 + ko);
    }
    const u16* Ab = smem + cur * 4096;
    const u16* Bb = smem + 8192 + cur * 4096;
    h16x8 af[4], bfr[4];
#pragma unroll
    for (int mt = 0; mt < 4; ++mt)
      af[mt] = *(const h16x8*)&Ab[(wr * 64 + mt * 16 + lr) * 32 + ((quad ^ swz) << 3)];
#pragma unroll
    for (int ct = 0; ct < 4; ++ct)
      bfr[ct] = *(const h16x8*)&Bb[(wc * 64 + ct * 16 + lr) * 32 + ((quad ^ swz) << 3)];
#pragma unroll
    for (int mt = 0; mt < 4; ++mt)
#pragma unroll
      for (int ct = 0; ct < 4; ++ct)
        acc[mt][ct] = MFMA32(af[mt], bfr[ct], acc[mt][ct]);
  }

#pragma unroll
  for (int mt = 0; mt < 4; ++mt)
#pragma unroll
    for (int reg = 0; reg < 4; ++reg) {
      const long row = m0 + wr * 64 + mt * 16 + quad * 4 + reg;
#pragma unroll
      for (int ct = 0; ct < 4; ++ct) {
        const long col = n0 + wc * 64 + ct * 16 + lr;
        Cout[row * N + col] = acc[mt][ct][reg] + bias[col];
      }
    }
}

// ---------------- split-K causal flash attention ----------------
// Register-resident P^T (S^T via operand-swap; C-layout == MFMA16 B-frag).
// K and pre-transposed V^T staged via async gld16, double-buffered LDS,
// ONE barrier per iteration. cvt_pkrtz packing; l accumulated pre-truncation.
__device__ __constant__ unsigned char ATAB[48] = {
    15,      16,      17,      18,      19,      20,      21,      22,
    23,      24,      25,      26,      27,      28,      29,      30,
    31,      31 | 64, 14,      30 | 64, 13,      29 | 64, 12,      28 | 64,
    11,      27 | 64, 10,      26 | 64, 9,       25 | 64, 8,       24 | 64,
    7,       23 | 64, 6,       22 | 64, 5,       21 | 64, 4,       20 | 64,
    3,       19 | 64, 2,       18 | 64, 1,       17 | 64, 0,       16 | 64};

__global__ __launch_bounds__(256, 4) void attn_part(const u16* __restrict__ qkv,
                                                    const u16* __restrict__ vt,
                                                    u16* __restrict__ attno,
                                                    u16* __restrict__ Opart,
                                                    float* __restrict__ lpart) {
  __shared__ u16 smem[16384];  // [0:4096)=K0 [4096:8192)=K1 [8192:12288)=V0 [12288:)=V1
  const int t = threadIdx.x;
  const int lane = t & 63, wave = t >> 6;
  const int lr = lane & 15, quad = lane >> 4;
  const int enc = ATAB[blockIdx.x];
  const int qc = enc & 63, part = enc >> 6;
  const int h = blockIdx.y, b = blockIdx.z;
  const long rowbase = (long)b * SEQ;
  const int q0 = qc * 64;
  const int kts = part * 16;
  const int kte = min(kts + 16, qc + 1);
  const int niter = kte - kts;

  // Q fragments straight from global (row = own query)
  h16x8 aq[2];
  {
    const u16* qrow = qkv + (rowbase + q0 + wave * 16 + lr) * 3072 + h * 64;
    aq[0] = *(const h16x8*)(qrow + quad * 8);
    aq[1] = *(const h16x8*)(qrow + 32 + quad * 8);
  }

  // staging: chunk L -> row=L>>3, source col-chunk = (L&7)^(row&7)  (XOR swizzle)
  const int L0 = t, L1 = t + 256;
  const int row0 = L0 >> 3, sc0 = ((L0 & 7) ^ (row0 & 7)) * 8;
  const int row1 = L1 >> 3, sc1 = ((L1 & 7) ^ (row1 & 7)) * 8;
  const u16* Kg0 = qkv + (rowbase + kts * 64 + row0) * 3072 + 1024 + h * 64 + sc0;
  const u16* Kg1 = qkv + (rowbase + kts * 64 + row1) * 3072 + 1024 + h * 64 + sc1;
  const u16* vtg = vt + (long)(b * 16 + h) * 64 * SEQ + kts * 64;
  const u16* Vg0 = vtg + (long)row0 * SEQ + sc0;  // row = d
  const u16* Vg1 = vtg + (long)row1 * SEQ + sc1;
  u16* const Kd0[2] = {smem + L0 * 8, smem + 4096 + L0 * 8};
  u16* const Kd1[2] = {smem + L1 * 8, smem + 4096 + L1 * 8};
  u16* const Vd0[2] = {smem + 8192 + L0 * 8, smem + 12288 + L0 * 8};
  u16* const Vd1[2] = {smem + 8192 + L1 * 8, smem + 12288 + L1 * 8};

  // tile kts -> buffer 0; advance pointers to next tile
  gld16(Kd0[0], Kg0); gld16(Kd1[0], Kg1);
  gld16(Vd0[0], Vg0); gld16(Vd1[0], Vg1);
  Kg0 += 64 * 3072; Kg1 += 64 * 3072; Vg0 += 64; Vg1 += 64;

  f32x4 acc_o[4];
#pragma unroll
  for (int r = 0; r < 4; ++r) acc_o[r] = (f32x4){0.f, 0.f, 0.f, 0.f};
  float lacc = 0.f;

  const int fswK = lr & 7;
  const int qg = q0 + wave * 16 + lr;

  for (int it = 0; it < niter; ++it) {
    const int kt = kts + it;
    const int cur = it & 1, nxt = cur ^ 1;
    __syncthreads();  // (a) buf[cur] staged (vmcnt drain); (b) buf[nxt] reads done

    if (it + 1 < niter) {  // prefetch next tile; drains at NEXT barrier
      gld16(Kd0[nxt], Kg0); gld16(Kd1[nxt], Kg1);
      gld16(Vd0[nxt], Vg0); gld16(Vd1[nxt], Vg1);
      Kg0 += 64 * 3072; Kg1 += 64 * 3072; Vg0 += 64; Vg1 += 64;
    }

    const u16* Kc = smem + (cur ? 4096 : 0);
    const u16* Vc = smem + 8192 + (cur ? 4096 : 0);

    // S^T = K Q^T : sacc[kk] holds S^T[key=kk*16+quad*4+reg][q=lr]
    f32x4 sacc[4];
#pragma unroll
    for (int kk = 0; kk < 4; ++kk) sacc[kk] = (f32x4){0.f, 0.f, 0.f, 0.f};
#pragma unroll
    for (int ks = 0; ks < 2; ++ks)
#pragma unroll
      for (int kk = 0; kk < 4; ++kk) {
        h16x8 af = *(const h16x8*)&Kc[(kk * 16 + lr) * 64 + (((ks * 4 + quad) ^ fswK) << 3)];
        sacc[kk] = MFMA32(af, aq[ks], sacc[kk]);
      }

    // P^T = exp2(S^T): cvt_pkrtz pack to f16; l from pre-truncation p
    const bool diag = (kt == qc);
    h16x4 pk[4];
#pragma unroll
    for (int kk = 0; kk < 4; ++kk) {
      float p[4];
#pragma unroll
      for (int reg = 0; reg < 4; ++reg) p[reg] = EXP2(sacc[kk][reg]);
      if (diag) {
        const int key = kt * 64 + kk * 16 + quad * 4;
#pragma unroll
        for (int reg = 0; reg < 4; ++reg) p[reg] = (key + reg <= qg) ? p[reg] : 0.f;
      }
      lacc += (p[0] + p[1]) + (p[2] + p[3]);
      union { h16x2 h2[2]; h16x4 v; } pu;
      pu.h2[0] = PKH2(p[0], p[1]);
      pu.h2[1] = PKH2(p[2], p[3]);
      pk[kk] = pu.v;
    }

    // O^T += V^T P^T  (A-frag: b64 from swizzled V^T; B-frag: pk regs)
#pragma unroll
    for (int dt = 0; dt < 4; ++dt) {
      const int d = dt * 16 + lr;
      const int dsw = d & 7;
      const int base = d * 64 + ((quad & 1) << 2);
#pragma unroll
      for (int kk = 0; kk < 4; ++kk) {
        const h16x4 vf = *(const h16x4*)&Vc[base + (((kk * 2 + (quad >> 1)) ^ dsw) << 3)];
        acc_o[dt] = MFMA16(vf, pk[kk], acc_o[dt]);
      }
    }
  }

  // cross-quad l reduction: every lane ends with l for query q=lr
  lacc += __shfl_xor(lacc, 16, 64);
  lacc += __shfl_xor(lacc, 32, 64);
  const float scale = (qc < 16) ? (1.f / lacc) : 1.f;

  // transpose O^T(regs) -> smem[q][d] stride 72, then coalesced store
  __syncthreads();  // all waves done with K/V buffers
#pragma unroll
  for (int dt = 0; dt < 4; ++dt) {
    s16x4 ov;
#pragma unroll
    for (int reg = 0; reg < 4; ++reg) ov[reg] = (short)f2h(acc_o[dt][reg] * scale);
    *(s16x4*)&smem[(wave * 16 + lr) * 72 + dt * 16 + quad * 4] = ov;
  }
  if (qc >= 16 && quad == 0) {
    const int slot = ((b * 16 + h) * 32 + (qc - 16) * 2 + part);
    lpart[slot * 64 + wave * 16 + lr] = lacc;
  }
  __syncthreads();

  const int row = t >> 2, ch = (t & 3) * 16;
  uint4 w0 = *(const uint4*)&smem[row * 72 + ch];
  uint4 w1 = *(const uint4*)&smem[row * 72 + ch + 8];
  if (qc < 16) {
    u16* dst = attno + (rowbase + q0 + row) * 1024 + h * 64 + ch;
    *(uint4*)dst = w0;
    *(uint4*)(dst + 8) = w1;
  } else {
    const int slot = ((b * 16 + h) * 32 + (qc - 16) * 2 + part);
    u16* dst = Opart + (size_t)slot * 4096 + row * 64 + ch;
    *(uint4*)dst = w0;
    *(uint4*)(dst + 8) = w1;
  }
}

// ---------------- combine: sum 2 partials, normalize ----------------
__global__ __launch_bounds__(256) void attn_combine(const u16* __restrict__ Opart,
                                                    const float* __restrict__ lpart,
                                                    u16* __restrict__ attno) {
  const int qcp = blockIdx.x;  // qc = 16 + qcp
  const int h = blockIdx.y, b = blockIdx.z;
  const int t = threadIdx.x;
  const int r = t >> 2, cc = (t & 3) * 16;
  const int slot0 = ((b * 16 + h) * 32 + qcp * 2);
  const u16* p0 = Opart + (size_t)slot0 * 4096 + r * 64 + cc;
  const u16* p1 = p0 + 4096;
  const float inv = 1.f / (lpart[slot0 * 64 + r] + lpart[(slot0 + 1) * 64 + r]);

  union { uint4 v[2]; u16 s[16]; } a, c;
  union { uint4 v[2]; u16 s[16]; } bB;
  a.v[0] = *(const uint4*)p0; a.v[1] = *(const uint4*)(p0 + 8);
  bB.v[0] = *(const uint4*)p1; bB.v[1] = *(const uint4*)(p1 + 8);
#pragma unroll
  for (int j = 0; j < 16; ++j) {
    const float f = h2f(a.s[j]) + h2f(bB.s[j]);
    c.s[j] = f2h(f * inv);
  }
  const long gi = (long)(16 + qcp) * 64 + r;
  u16* dst = attno + ((long)b * SEQ + gi) * 1024 + h * 64 + cc;
  *(uint4*)dst = c.v[0];
  *(uint4*)(dst + 8) = c.v[1];
}

extern "C" void kernel_launch(void* const* d_in, const int* in_sizes, int n_in,
                              void* d_out, int out_size, void* d_ws, size_t ws_size,
                              hipStream_t stream) {
  const float* x    = (const float*)d_in[0];  // (4,2048,1024)
  const float* Wqkv = (const float*)d_in[1];  // (1024,3072)
  const float* bqkv = (const float*)d_in[2];  // (3072,)
  const float* Wout = (const float*)d_in[3];  // (1024,1024)
  const float* bout = (const float*)d_in[4];  // (1024,)

  u16* xb    = (u16*)d_ws;                       // 8192x1024 f16 (dead after gemm0)
  u16* wqkvT = xb    + (size_t)M_TOK * 1024;     // 3072x1024 f16
  u16* woutT = wqkvT + (size_t)3072 * 1024;      // 1024x1024 f16
  u16* qkv   = woutT + (size_t)1024 * 1024;      // 8192x3072 f16 (Q pre-scaled; V region unused)
  u16* attno = qkv   + (size_t)M_TOK * 3072;     // 8192x1024 f16
  float* lpart = (float*)(attno + (size_t)M_TOK * 1024);  // 2048x64 f32
  u16* vtbuf = (u16*)(lpart + 2048 * 64);        // 64bh x 64d x 2048s f16 (16.8 MB)
  u16* Opart = xb;  // alias: 2048 slots x 4096 f16, fits xb exactly

  cvt_f32_f16<<<(M_TOK * 1024) / 1024, 256, 0, stream>>>(x, xb);
  transpose_cvt<<<dim3(3072 / 32, 1024 / 32), dim3(32, 8), 0, stream>>>(Wqkv, wqkvT, 1024, 3072);
  transpose_cvt<<<dim3(1024 / 32, 1024 / 32), dim3(32, 8), 0, stream>>>(Wout, woutT, 1024, 1024);

  gemm_qkv<<<dim3(3072 / 128, M_TOK / 128), 256, 0, stream>>>(
      xb, wqkvT, bqkv, qkv, vtbuf, M_TOK, 3072, 1024);

  attn_part<<<dim3(48, 16, BATCH), 256, 0, stream>>>(qkv, vtbuf, attno, Opart, lpart);
  attn_combine<<<dim3(16, 16, BATCH), 256, 0, stream>>>(Opart, lpart, attno);

  gemm_proj<<<dim3(1024 / 128, M_TOK / 128), 256, 0, stream>>>(
      attno, woutT, bout, (float*)d_out, M_TOK, 1024, 1024);
}

// Round 17
// 266.126 us; speedup vs baseline: 1.0632x; 1.0632x over previous
//
#include <hip/hip_runtime.h>

typedef unsigned short u16;
typedef short s16x4 __attribute__((ext_vector_type(4)));
typedef _Float16 h16x8 __attribute__((ext_vector_type(8)));
typedef _Float16 h16x4 __attribute__((ext_vector_type(4)));
typedef _Float16 h16x2 __attribute__((ext_vector_type(2)));
typedef __fp16 fp16x2 __attribute__((ext_vector_type(2)));
typedef float f32x4 __attribute__((ext_vector_type(4)));

#define SEQ 2048
#define BATCH 4
#define M_TOK (BATCH * SEQ)  // 8192
// 1/sqrt(64) * log2(e): folded into Q so softmax is a bare exp2
#define QK_SCALE 0.18033688011112043f

#if __has_builtin(__builtin_amdgcn_exp2f)
#define EXP2(x) __builtin_amdgcn_exp2f(x)
#else
#define EXP2(x) exp2f(x)
#endif

// ---- K=32 f16 MFMA (main GEMM + QK^T) ----
#if __has_builtin(__builtin_amdgcn_mfma_f32_16x16x32_f16)
#define MFMA32(A, B, C) __builtin_amdgcn_mfma_f32_16x16x32_f16((A), (B), (C), 0, 0, 0)
#else
static __device__ __forceinline__ f32x4 mfma32_asm(h16x8 a, h16x8 b, f32x4 c) {
  asm volatile("v_mfma_f32_16x16x32_f16 %0, %1, %2, %0"
               : "+v"(c)
               : "v"(a), "v"(b));
  return c;
}
#define MFMA32(A, B, C) mfma32_asm((A), (B), (C))
#endif

// ---- K=16 f16 MFMA (PV consumes P^T straight from S^T C-layout regs) ----
#if __has_builtin(__builtin_amdgcn_mfma_f32_16x16x16f16)
#define MFMA16(A, B, C) __builtin_amdgcn_mfma_f32_16x16x16f16((A), (B), (C), 0, 0, 0)
#elif __has_builtin(__builtin_amdgcn_mfma_f32_16x16x16_f16)
#define MFMA16(A, B, C) __builtin_amdgcn_mfma_f32_16x16x16_f16((A), (B), (C), 0, 0, 0)
#else
static __device__ __forceinline__ f32x4 mfma16_asm(h16x4 a, h16x4 b, f32x4 c) {
  asm volatile("v_mfma_f32_16x16x16_f16 %0, %1, %2, %0"
               : "+v"(c)
               : "v"(a), "v"(b));
  return c;
}
#define MFMA16(A, B, C) mfma16_asm((A), (B), (C))
#endif

// f32 -> f16 (RNE) as raw u16
__device__ __forceinline__ u16 f2h(float f) {
  union { _Float16 h; u16 u; } v;
  v.h = (_Float16)f;
  return v.u;
}
// raw u16 f16 -> f32
__device__ __forceinline__ float h2f(u16 u) {
  union { u16 u; _Float16 h; } v;
  v.u = u;
  return (float)v.h;
}

// pack two f32 -> two f16 in one dword (v_cvt_pkrtz_f16_f32)
#if __has_builtin(__builtin_amdgcn_cvt_pkrtz)
static __device__ __forceinline__ h16x2 pkh2(float lo, float hi) {
  union { fp16x2 a; h16x2 b; } u;
  u.a = __builtin_amdgcn_cvt_pkrtz(lo, hi);
  return u.b;
}
#else
static __device__ __forceinline__ h16x2 pkh2(float lo, float hi) {
  h16x2 r; r[0] = (_Float16)lo; r[1] = (_Float16)hi; return r;
}
#endif
#define PKH2(lo, hi) pkh2((lo), (hi))

// async global->LDS 16B: LDS dest is wave-uniform base + lane*16
__device__ __forceinline__ void gld16(u16* lds, const u16* g) {
  __builtin_amdgcn_global_load_lds(
      (const __attribute__((address_space(1))) unsigned int*)g,
      (__attribute__((address_space(3))) unsigned int*)lds, 16, 0, 0);
}

// schedule/sync primitives for the counted-vmcnt pipeline
#define VMCNT4 asm volatile("s_waitcnt vmcnt(4)" ::: "memory")
#define VMCNT0 asm volatile("s_waitcnt vmcnt(0)" ::: "memory")
#define LGK0 asm volatile("s_waitcnt lgkmcnt(0)" ::: "memory")
#define SCHEDB __builtin_amdgcn_sched_barrier(0)
#define BARRIER                                                                \
  do {                                                                         \
    SCHEDB;                                                                    \
    __builtin_amdgcn_s_barrier();                                              \
    SCHEDB;                                                                    \
  } while (0)

// ---------------- prep: f32 -> f16 cast ----------------
__global__ __launch_bounds__(256) void cvt_f32_f16(const float* __restrict__ in,
                                                   u16* __restrict__ out) {
  int i = (blockIdx.x * 256 + threadIdx.x) * 4;
  float4 f = *(const float4*)(in + i);
  ushort4 o;
  o.x = f2h(f.x); o.y = f2h(f.y); o.z = f2h(f.z); o.w = f2h(f.w);
  *(ushort4*)(out + i) = o;
}

// ---------------- prep: W (KxN f32) -> Wt (NxK f16) ----------------
__global__ __launch_bounds__(256) void transpose_cvt(const float* __restrict__ W,
                                                     u16* __restrict__ Wt, int K, int N) {
  __shared__ float tile[32][33];
  const int tx = threadIdx.x, ty = threadIdx.y;
  const int n0 = blockIdx.x * 32, k0 = blockIdx.y * 32;
  for (int j = ty; j < 32; j += 8)
    tile[j][tx] = W[(size_t)(k0 + j) * N + n0 + tx];
  __syncthreads();
  for (int j = ty; j < 32; j += 8)
    Wt[(size_t)(n0 + j) * K + k0 + tx] = f2h(tile[tx][j]);
}

// ---------------- QKV GEMM: 256x256 tile, BK=64, counted-vmcnt pipeline ----------------
// (verified rounds 9/12: 268.7/269.5 us total) 512 threads, double-buffered 128KB LDS,
// vmcnt(4) ledger; never drains to 0 in steady state.
__global__ __launch_bounds__(512, 2) void gemm_qkv(const u16* __restrict__ A,
                                                   const u16* __restrict__ Bt,
                                                   const float* __restrict__ bias,
                                                   u16* __restrict__ Cout,
                                                   u16* __restrict__ Vtout,
                                                   int M, int N, int K) {
  __shared__ u16 smem[65536];  // 128KB: 2 x (A 16K u16 + B 16K u16)
  const int t = threadIdx.x;
  const int lane = t & 63, wave = t >> 6;
  const int wr = wave >> 2;  // 0,1  (M)
  const int wc = wave & 3;   // 0..3 (N)
  const int lr = lane & 15, quad = lane >> 4;
  const int swzl = (lr >> 1) & 3;
  const int qs8 = ((quad ^ swzl) << 3);
  const long m0 = (long)blockIdx.y * 256, n0 = (long)blockIdx.x * 256;

  const int L0 = t, L1 = t + 512;
  const int rS0 = L0 >> 2, sS0 = ((L0 & 3) ^ ((L0 >> 3) & 3)) * 8;
  const int rS1 = L1 >> 2, sS1 = ((L1 & 3) ^ ((L1 >> 3) & 3)) * 8;
  const u16* Ag0 = A + (m0 + rS0) * (long)K + sS0;
  const u16* Ag1 = A + (m0 + rS1) * (long)K + sS1;
  const u16* Bg0 = Bt + (n0 + rS0) * (long)K + sS0;
  const u16* Bg1 = Bt + (n0 + rS1) * (long)K + sS1;

#define STAGE_A(c, kh, gofs)                                    \
  do {                                                          \
    gld16(smem + (c)*32768 + (kh)*8192 + L0 * 8, Ag0 + (gofs)); \
    gld16(smem + (c)*32768 + (kh)*8192 + L1 * 8, Ag1 + (gofs)); \
  } while (0)
#define STAGE_B(c, kh, gofs)                                            \
  do {                                                                  \
    gld16(smem + (c)*32768 + 16384 + (kh)*8192 + L0 * 8, Bg0 + (gofs)); \
    gld16(smem + (c)*32768 + 16384 + (kh)*8192 + L1 * 8, Bg1 + (gofs)); \
  } while (0)

  int aoff[8], boff[4];
#pragma unroll
  for (int mf = 0; mf < 8; ++mf) aoff[mf] = (wr * 128 + mf * 16 + lr) * 32 + qs8;
#pragma unroll
  for (int nf = 0; nf < 4; ++nf) boff[nf] = (wc * 64 + nf * 16 + lr) * 32 + qs8;

  f32x4 acc[8][4];
#pragma unroll
  for (int i = 0; i < 8; ++i)
#pragma unroll
    for (int j = 0; j < 4; ++j) acc[i][j] = (f32x4){0.f, 0.f, 0.f, 0.f};

  STAGE_A(0, 0, 0);
  STAGE_B(0, 0, 0);
  STAGE_A(0, 1, 32);
  STAGE_B(0, 1, 32);

  const int NT = K >> 6;  // 16
  for (int kt = 0; kt < NT; ++kt) {
    const int c = kt & 1, nc = c ^ 1;
    const u16* Ab = smem + c * 32768;
    const u16* Bb = Ab + 16384;
    const bool pf = (kt + 1 < NT);
    const long go = (long)(kt + 1) * 64;

    VMCNT4;  // retire {A0,B0}(kt)
    BARRIER;

    h16x8 bf[4], af[4];
    // ---- phase a0 ----
    if (pf) STAGE_A(nc, 0, go);
#pragma unroll
    for (int nf = 0; nf < 4; ++nf) bf[nf] = *(const h16x8*)&Bb[boff[nf]];
#pragma unroll
    for (int mf = 0; mf < 4; ++mf) af[mf] = *(const h16x8*)&Ab[aoff[mf]];
    LGK0; SCHEDB;
    __builtin_amdgcn_s_setprio(1);
#pragma unroll
    for (int mf = 0; mf < 4; ++mf)
#pragma unroll
      for (int nf = 0; nf < 4; ++nf)
        acc[mf][nf] = MFMA32(af[mf], bf[nf], acc[mf][nf]);
    __builtin_amdgcn_s_setprio(0);
    SCHEDB;
    // ---- phase a1 ----
    if (pf) STAGE_B(nc, 0, go);
#pragma unroll
    for (int mf = 0; mf < 4; ++mf) af[mf] = *(const h16x8*)&Ab[aoff[mf + 4]];
    LGK0; SCHEDB;
    __builtin_amdgcn_s_setprio(1);
#pragma unroll
    for (int mf = 0; mf < 4; ++mf)
#pragma unroll
      for (int nf = 0; nf < 4; ++nf)
        acc[mf + 4][nf] = MFMA32(af[mf], bf[nf], acc[mf + 4][nf]);
    __builtin_amdgcn_s_setprio(0);
    SCHEDB;

    if (pf) { VMCNT4; } else { VMCNT0; }  // retire {A1,B1}(kt)
    BARRIER;

    // ---- phase b0 ----
    if (pf) STAGE_A(nc, 1, go + 32);
#pragma unroll
    for (int nf = 0; nf < 4; ++nf) bf[nf] = *(const h16x8*)&Bb[8192 + boff[nf]];
#pragma unroll
    for (int mf = 0; mf < 4; ++mf) af[mf] = *(const h16x8*)&Ab[8192 + aoff[mf]];
    LGK0; SCHEDB;
    __builtin_amdgcn_s_setprio(1);
#pragma unroll
    for (int mf = 0; mf < 4; ++mf)
#pragma unroll
      for (int nf = 0; nf < 4; ++nf)
        acc[mf][nf] = MFMA32(af[mf], bf[nf], acc[mf][nf]);
    __builtin_amdgcn_s_setprio(0);
    SCHEDB;
    // ---- phase b1 ----
    if (pf) STAGE_B(nc, 1, go + 32);
#pragma unroll
    for (int mf = 0; mf < 4; ++mf) af[mf] = *(const h16x8*)&Ab[8192 + aoff[mf + 4]];
    LGK0; SCHEDB;
    __builtin_amdgcn_s_setprio(1);
#pragma unroll
    for (int mf = 0; mf < 4; ++mf)
#pragma unroll
      for (int nf = 0; nf < 4; ++nf)
        acc[mf + 4][nf] = MFMA32(af[mf], bf[nf], acc[mf + 4][nf]);
    __builtin_amdgcn_s_setprio(0);
    SCHEDB;
  }
#undef STAGE_A
#undef STAGE_B

  // ---------------- epilogue via LDS tile (2 row-half passes) ----------------
  const float qs = (n0 < 1024) ? QK_SCALE : 1.0f;
  float bv[4];
#pragma unroll
  for (int nf = 0; nf < 4; ++nf) bv[nf] = bias[n0 + wc * 64 + nf * 16 + lr];

  __syncthreads();  // staging dead; reuse LDS

  if (n0 < 2048) {
#pragma unroll
    for (int p = 0; p < 2; ++p) {
      if (wr == p) {
#pragma unroll
        for (int mf = 0; mf < 8; ++mf)
#pragma unroll
          for (int nf = 0; nf < 4; ++nf) {
            const int col = wc * 64 + nf * 16 + lr;
            const int lrow = mf * 16 + quad * 4;
#pragma unroll
            for (int reg = 0; reg < 4; ++reg)
              smem[(lrow + reg) * 264 + col] = f2h((acc[mf][nf][reg] + bv[nf]) * qs);
          }
      }
      __syncthreads();
#pragma unroll
      for (int i = 0; i < 8; ++i) {
        const int ch = i * 512 + t;  // 4096 chunks of 8 u16
        const int row = ch >> 5, cc = (ch & 31) * 8;
        *(uint4*)&Cout[(m0 + p * 128 + row) * (long)N + n0 + cc] =
            *(const uint4*)&smem[row * 264 + cc];
      }
      __syncthreads();
    }
  } else {
    const int bb = (int)(m0 >> 11);
    const int sbase = (int)(m0 & 2047);
    const long vrow0 = (long)bb * 1024 + (n0 - 2048);  // (b*16+h)*64 + d
#pragma unroll
    for (int p = 0; p < 2; ++p) {
      if (wr == p) {
#pragma unroll
        for (int mf = 0; mf < 8; ++mf)
#pragma unroll
          for (int nf = 0; nf < 4; ++nf) {
            const int col = wc * 64 + nf * 16 + lr;
            const int lrow = mf * 16 + quad * 4;
            s16x4 ov;
#pragma unroll
            for (int reg = 0; reg < 4; ++reg)
              ov[reg] = (short)f2h(acc[mf][nf][reg] + bv[nf]);
            *(s16x4*)&smem[col * 136 + lrow] = ov;
          }
      }
      __syncthreads();
#pragma unroll
      for (int i = 0; i < 8; ++i) {
        const int ch = i * 512 + t;  // 256 cols x 16 s-chunks
        const int col = ch >> 4, s0 = (ch & 15) * 8;
        *(uint4*)&Vtout[(vrow0 + col) * (long)SEQ + sbase + p * 128 + s0] =
            *(const uint4*)&smem[col * 136 + s0];
      }
      __syncthreads();
    }
  }
}

// ---------------- proj GEMM: 128x128 tile, BK=32 (round-4 verified structure) ----------------
__global__ __launch_bounds__(256, 3) void gemm_proj(const u16* __restrict__ A,
                                                    const u16* __restrict__ Bt,
                                                    const float* __restrict__ bias,
                                                    float* __restrict__ Cout,
                                                    int M, int N, int K) {
  __shared__ u16 smem[16640];
  const int t = threadIdx.x;
  const int lane = t & 63, wave = t >> 6;
  const int wr = wave >> 1, wc = wave & 1;
  const int lr = lane & 15, quad = lane >> 4;
  const long m0 = (long)blockIdx.y * 128, n0 = (long)blockIdx.x * 128;

  const int r0 = t >> 2,         c0 = (((t) & 3) ^ ((r0 >> 1) & 3)) * 8;
  const int r1 = (t + 256) >> 2, c1 = (((t + 256) & 3) ^ ((r1 >> 1) & 3)) * 8;
  const u16* Ag0 = A + (m0 + r0) * (long)K + c0;
  const u16* Ag1 = A + (m0 + r1) * (long)K + c1;
  const u16* Bg0 = Bt + (n0 + r0) * (long)K + c0;
  const u16* Bg1 = Bt + (n0 + r1) * (long)K + c1;
  const int swz = (lr >> 1) & 3;

  f32x4 acc[4][4];
#pragma unroll
  for (int i = 0; i < 4; ++i)
#pragma unroll
    for (int j = 0; j < 4; ++j) acc[i][j] = (f32x4){0.f, 0.f, 0.f, 0.f};

  gld16(smem + t * 8, Ag0);
  gld16(smem + t * 8 + 2048, Ag1);
  gld16(smem + 8192 + t * 8, Bg0);
  gld16(smem + 8192 + t * 8 + 2048, Bg1);

  const int NIT = K >> 5;
  for (int it = 0; it < NIT; ++it) {
    const int cur = it & 1;
    __syncthreads();
    if (it + 1 < NIT) {
      const int nx = cur ^ 1;
      const long ko = (long)(it + 1) * 32;
      gld16(smem + nx * 4096 + t * 8, Ag0 + ko);
      gld16(smem + nx * 4096 + t * 8 + 2048, Ag1 + ko);
      gld16(smem + 8192 + nx * 4096 + t * 8, Bg0 + ko);
      gld16(smem + 8192 + nx * 4096 + t * 8 + 2048, Bg1 + ko);
    }
    const u16* Ab = smem + cur * 4096;
    const u16* Bb = smem + 8192 + cur * 4096;
    h16x8 af[4], bfr[4];
#pragma unroll
    for (int mt = 0; mt < 4; ++mt)
      af[mt] = *(const h16x8*)&Ab[(wr * 64 + mt * 16 + lr) * 32 + ((quad ^ swz) << 3)];
#pragma unroll
    for (int ct = 0; ct < 4; ++ct)
      bfr[ct] = *(const h16x8*)&Bb[(wc * 64 + ct * 16 + lr) * 32 + ((quad ^ swz) << 3)];
#pragma unroll
    for (int mt = 0; mt < 4; ++mt)
#pragma unroll
      for (int ct = 0; ct < 4; ++ct)
        acc[mt][ct] = MFMA32(af[mt], bfr[ct], acc[mt][ct]);
  }

#pragma unroll
  for (int mt = 0; mt < 4; ++mt)
#pragma unroll
    for (int reg = 0; reg < 4; ++reg) {
      const long row = m0 + wr * 64 + mt * 16 + quad * 4 + reg;
#pragma unroll
      for (int ct = 0; ct < 4; ++ct) {
        const long col = n0 + wc * 64 + ct * 16 + lr;
        Cout[row * N + col] = acc[mt][ct][reg] + bias[col];
      }
    }
}

// ---------------- split-K causal flash attention ----------------
// Register-resident P^T (S^T via operand-swap; C-layout == MFMA16 B-frag).
// K and pre-transposed V^T staged via async gld16, double-buffered LDS,
// ONE barrier per iteration. cvt_pkrtz packing; l accumulated pre-truncation.
__device__ __constant__ unsigned char ATAB[48] = {
    15,      16,      17,      18,      19,      20,      21,      22,
    23,      24,      25,      26,      27,      28,      29,      30,
    31,      31 | 64, 14,      30 | 64, 13,      29 | 64, 12,      28 | 64,
    11,      27 | 64, 10,      26 | 64, 9,       25 | 64, 8,       24 | 64,
    7,       23 | 64, 6,       22 | 64, 5,       21 | 64, 4,       20 | 64,
    3,       19 | 64, 2,       18 | 64, 1,       17 | 64, 0,       16 | 64};

__global__ __launch_bounds__(256, 4) void attn_part(const u16* __restrict__ qkv,
                                                    const u16* __restrict__ vt,
                                                    u16* __restrict__ attno,
                                                    u16* __restrict__ Opart,
                                                    float* __restrict__ lpart) {
  __shared__ u16 smem[16384];  // [0:4096)=K0 [4096:8192)=K1 [8192:12288)=V0 [12288:)=V1
  const int t = threadIdx.x;
  const int lane = t & 63, wave = t >> 6;
  const int lr = lane & 15, quad = lane >> 4;
  const int enc = ATAB[blockIdx.x];
  const int qc = enc & 63, part = enc >> 6;
  const int h = blockIdx.y, b = blockIdx.z;
  const long rowbase = (long)b * SEQ;
  const int q0 = qc * 64;
  const int kts = part * 16;
  const int kte = min(kts + 16, qc + 1);
  const int niter = kte - kts;

  // Q fragments straight from global (row = own query)
  h16x8 aq[2];
  {
    const u16* qrow = qkv + (rowbase + q0 + wave * 16 + lr) * 3072 + h * 64;
    aq[0] = *(const h16x8*)(qrow + quad * 8);
    aq[1] = *(const h16x8*)(qrow + 32 + quad * 8);
  }

  // staging: chunk L -> row=L>>3, source col-chunk = (L&7)^(row&7)  (XOR swizzle)
  const int L0 = t, L1 = t + 256;
  const int row0 = L0 >> 3, sc0 = ((L0 & 7) ^ (row0 & 7)) * 8;
  const int row1 = L1 >> 3, sc1 = ((L1 & 7) ^ (row1 & 7)) * 8;
  const u16* Kg0 = qkv + (rowbase + kts * 64 + row0) * 3072 + 1024 + h * 64 + sc0;
  const u16* Kg1 = qkv + (rowbase + kts * 64 + row1) * 3072 + 1024 + h * 64 + sc1;
  const u16* vtg = vt + (long)(b * 16 + h) * 64 * SEQ + kts * 64;
  const u16* Vg0 = vtg + (long)row0 * SEQ + sc0;  // row = d
  const u16* Vg1 = vtg + (long)row1 * SEQ + sc1;
  u16* const Kd0[2] = {smem + L0 * 8, smem + 4096 + L0 * 8};
  u16* const Kd1[2] = {smem + L1 * 8, smem + 4096 + L1 * 8};
  u16* const Vd0[2] = {smem + 8192 + L0 * 8, smem + 12288 + L0 * 8};
  u16* const Vd1[2] = {smem + 8192 + L1 * 8, smem + 12288 + L1 * 8};

  // tile kts -> buffer 0; advance pointers to next tile
  gld16(Kd0[0], Kg0); gld16(Kd1[0], Kg1);
  gld16(Vd0[0], Vg0); gld16(Vd1[0], Vg1);
  Kg0 += 64 * 3072; Kg1 += 64 * 3072; Vg0 += 64; Vg1 += 64;

  f32x4 acc_o[4];
#pragma unroll
  for (int r = 0; r < 4; ++r) acc_o[r] = (f32x4){0.f, 0.f, 0.f, 0.f};
  float lacc = 0.f;

  const int fswK = lr & 7;
  const int qg = q0 + wave * 16 + lr;

  for (int it = 0; it < niter; ++it) {
    const int kt = kts + it;
    const int cur = it & 1, nxt = cur ^ 1;
    __syncthreads();  // (a) buf[cur] staged (vmcnt drain); (b) buf[nxt] reads done

    if (it + 1 < niter) {  // prefetch next tile; drains at NEXT barrier
      gld16(Kd0[nxt], Kg0); gld16(Kd1[nxt], Kg1);
      gld16(Vd0[nxt], Vg0); gld16(Vd1[nxt], Vg1);
      Kg0 += 64 * 3072; Kg1 += 64 * 3072; Vg0 += 64; Vg1 += 64;
    }

    const u16* Kc = smem + (cur ? 4096 : 0);
    const u16* Vc = smem + 8192 + (cur ? 4096 : 0);

    // S^T = K Q^T : sacc[kk] holds S^T[key=kk*16+quad*4+reg][q=lr]
    f32x4 sacc[4];
#pragma unroll
    for (int kk = 0; kk < 4; ++kk) sacc[kk] = (f32x4){0.f, 0.f, 0.f, 0.f};
#pragma unroll
    for (int ks = 0; ks < 2; ++ks)
#pragma unroll
      for (int kk = 0; kk < 4; ++kk) {
        h16x8 af = *(const h16x8*)&Kc[(kk * 16 + lr) * 64 + (((ks * 4 + quad) ^ fswK) << 3)];
        sacc[kk] = MFMA32(af, aq[ks], sacc[kk]);
      }

    // P^T = exp2(S^T): cvt_pkrtz pack to f16; l from pre-truncation p
    const bool diag = (kt == qc);
    h16x4 pk[4];
#pragma unroll
    for (int kk = 0; kk < 4; ++kk) {
      float p[4];
#pragma unroll
      for (int reg = 0; reg < 4; ++reg) p[reg] = EXP2(sacc[kk][reg]);
      if (diag) {
        const int key = kt * 64 + kk * 16 + quad * 4;
#pragma unroll
        for (int reg = 0; reg < 4; ++reg) p[reg] = (key + reg <= qg) ? p[reg] : 0.f;
      }
      lacc += (p[0] + p[1]) + (p[2] + p[3]);
      union { h16x2 h2[2]; h16x4 v; } pu;
      pu.h2[0] = PKH2(p[0], p[1]);
      pu.h2[1] = PKH2(p[2], p[3]);
      pk[kk] = pu.v;
    }

    // O^T += V^T P^T  (A-frag: b64 from swizzled V^T; B-frag: pk regs)
#pragma unroll
    for (int dt = 0; dt < 4; ++dt) {
      const int d = dt * 16 + lr;
      const int dsw = d & 7;
      const int base = d * 64 + ((quad & 1) << 2);
#pragma unroll
      for (int kk = 0; kk < 4; ++kk) {
        const h16x4 vf = *(const h16x4*)&Vc[base + (((kk * 2 + (quad >> 1)) ^ dsw) << 3)];
        acc_o[dt] = MFMA16(vf, pk[kk], acc_o[dt]);
      }
    }
  }

  // cross-quad l reduction: every lane ends with l for query q=lr
  lacc += __shfl_xor(lacc, 16, 64);
  lacc += __shfl_xor(lacc, 32, 64);
  const float scale = (qc < 16) ? (1.f / lacc) : 1.f;

  // transpose O^T(regs) -> smem[q][d] stride 72, then coalesced store
  __syncthreads();  // all waves done with K/V buffers
#pragma unroll
  for (int dt = 0; dt < 4; ++dt) {
    s16x4 ov;
#pragma unroll
    for (int reg = 0; reg < 4; ++reg) ov[reg] = (short)f2h(acc_o[dt][reg] * scale);
    *(s16x4*)&smem[(wave * 16 + lr) * 72 + dt * 16 + quad * 4] = ov;
  }
  if (qc >= 16 && quad == 0) {
    const int slot = ((b * 16 + h) * 32 + (qc - 16) * 2 + part);
    lpart[slot * 64 + wave * 16 + lr] = lacc;
  }
  __syncthreads();

  const int row = t >> 2, ch = (t & 3) * 16;
  uint4 w0 = *(const uint4*)&smem[row * 72 + ch];
  uint4 w1 = *(const uint4*)&smem[row * 72 + ch + 8];
  if (qc < 16) {
    u16* dst = attno + (rowbase + q0 + row) * 1024 + h * 64 + ch;
    *(uint4*)dst = w0;
    *(uint4*)(dst + 8) = w1;
  } else {
    const int slot = ((b * 16 + h) * 32 + (qc - 16) * 2 + part);
    u16* dst = Opart + (size_t)slot * 4096 + row * 64 + ch;
    *(uint4*)dst = w0;
    *(uint4*)(dst + 8) = w1;
  }
}

// ---------------- combine: sum 2 partials, normalize ----------------
__global__ __launch_bounds__(256) void attn_combine(const u16* __restrict__ Opart,
                                                    const float* __restrict__ lpart,
                                                    u16* __restrict__ attno) {
  const int qcp = blockIdx.x;  // qc = 16 + qcp
  const int h = blockIdx.y, b = blockIdx.z;
  const int t = threadIdx.x;
  const int r = t >> 2, cc = (t & 3) * 16;
  const int slot0 = ((b * 16 + h) * 32 + qcp * 2);
  const u16* p0 = Opart + (size_t)slot0 * 4096 + r * 64 + cc;
  const u16* p1 = p0 + 4096;
  const float inv = 1.f / (lpart[slot0 * 64 + r] + lpart[(slot0 + 1) * 64 + r]);

  union { uint4 v[2]; u16 s[16]; } a, c;
  union { uint4 v[2]; u16 s[16]; } bB;
  a.v[0] = *(const uint4*)p0; a.v[1] = *(const uint4*)(p0 + 8);
  bB.v[0] = *(const uint4*)p1; bB.v[1] = *(const uint4*)(p1 + 8);
#pragma unroll
  for (int j = 0; j < 16; ++j) {
    const float f = h2f(a.s[j]) + h2f(bB.s[j]);
    c.s[j] = f2h(f * inv);
  }
  const long gi = (long)(16 + qcp) * 64 + r;
  u16* dst = attno + ((long)b * SEQ + gi) * 1024 + h * 64 + cc;
  *(uint4*)dst = c.v[0];
  *(uint4*)(dst + 8) = c.v[1];
}

extern "C" void kernel_launch(void* const* d_in, const int* in_sizes, int n_in,
                              void* d_out, int out_size, void* d_ws, size_t ws_size,
                              hipStream_t stream) {
  const float* x    = (const float*)d_in[0];  // (4,2048,1024)
  const float* Wqkv = (const float*)d_in[1];  // (1024,3072)
  const float* bqkv = (const float*)d_in[2];  // (3072,)
  const float* Wout = (const float*)d_in[3];  // (1024,1024)
  const float* bout = (const float*)d_in[4];  // (1024,)

  u16* xb    = (u16*)d_ws;                       // 8192x1024 f16 (dead after gemm0)
  u16* wqkvT = xb    + (size_t)M_TOK * 1024;     // 3072x1024 f16
  u16* woutT = wqkvT + (size_t)3072 * 1024;      // 1024x1024 f16
  u16* qkv   = woutT + (size_t)1024 * 1024;      // 8192x3072 f16 (Q pre-scaled; V region unused)
  u16* attno = qkv   + (size_t)M_TOK * 3072;     // 8192x1024 f16
  float* lpart = (float*)(attno + (size_t)M_TOK * 1024);  // 2048x64 f32
  u16* vtbuf = (u16*)(lpart + 2048 * 64);        // 64bh x 64d x 2048s f16 (16.8 MB)
  u16* Opart = xb;  // alias: 2048 slots x 4096 f16, fits xb exactly

  cvt_f32_f16<<<(M_TOK * 1024) / 1024, 256, 0, stream>>>(x, xb);
  transpose_cvt<<<dim3(3072 / 32, 1024 / 32), dim3(32, 8), 0, stream>>>(Wqkv, wqkvT, 1024, 3072);
  transpose_cvt<<<dim3(1024 / 32, 1024 / 32), dim3(32, 8), 0, stream>>>(Wout, woutT, 1024, 1024);

  gemm_qkv<<<dim3(3072 / 256, M_TOK / 256), 512, 0, stream>>>(
      xb, wqkvT, bqkv, qkv, vtbuf, M_TOK, 3072, 1024);

  attn_part<<<dim3(48, 16, BATCH), 256, 0, stream>>>(qkv, vtbuf, attno, Opart, lpart);
  attn_combine<<<dim3(16, 16, BATCH), 256, 0, stream>>>(Opart, lpart, attno);

  gemm_proj<<<dim3(1024 / 128, M_TOK / 128), 256, 0, stream>>>(
      attno, woutT, bout, (float*)d_out, M_TOK, 1024, 1024);
}